// Round 8
// baseline (209.327 us; speedup 1.0000x reference)
//
#include <hip/hip_runtime.h>
#include <hip/hip_bf16.h>

// GCN: 2x GCNConv(128->128) + LeakyReLU(0.1) + mean over channels.
// N=50000, E=1600000, D=128, fp32 in/out.
//
// R18: delete the K2 scan kernel. Order within a dst-bucket is irrelevant
//   (K3 sort re-groups), so scatter bases need not be deterministic:
//   K2-scatter reserves ranges dynamically via ONE global atomicAdd per
//   (block,bucket) (76K atomics total). H[BK*CHN] and the per-bucket chunk
//   scan are deleted. Bucket totals accumulate in K1 (LDS hist -> 196 global
//   adds/block); the 196-value exclusive scan runs in K1's LAST-ticket block
//   (R9b K2's validated spin-free pattern: ticket + atomicAdd(p,0) coherent
//   reads; NO RMW spins (R13 disaster), NO grid.sync (R11 ~45us each)).
//   Ticket/Tg zeroed by hipMemsetAsync (capture-proven in R13).
// Gather: R9b 2-deep VERBATIM (56.4us). R12/R14/R17 all showed deeper/
//   restructured pipelines are neutral-to-worse; inner loop is at its
//   structural floor (VALU floor ~26us + random 256B-row traffic).
// K3: sort || gemm(128 rows/block) -- R14 verbatim. K5 out verbatim.
// Math (verified R2-R8): h[u]=bf16((x@W1)[u]);  g UNSCALED, dinv per-edge fma:
//   mg[u]=dinv[u]*dot(lrelu(dinv[u]*sum_{n in N(u)+u} dinv[n]*h[n] + b1), mean_j W2[:,j]);
//   out[v]=dinv[v]*(mg[v]+sum mg[nbr]) + mean(b2).

#define N_NODES 50000
#define NPAD 50048
#define D 128
#define BK 196           // node buckets: v>>8
#define CHUNK 4096       // edges per hist/scatter block

typedef unsigned int uint;
typedef unsigned short u16;
typedef __attribute__((ext_vector_type(8))) short short8;   // 8 bf16 (4 VGPRs)
typedef __attribute__((ext_vector_type(4))) float floatx4;

__device__ __forceinline__ u16 cvt_bf16(float f) {
    uint u = __float_as_uint(f);
    return (u16)((u + 0x7fffu + ((u >> 16) & 1u)) >> 16);   // RNE
}
__device__ __forceinline__ uint pack_bf2(float a, float b) {
    return (uint)cvt_bf16(a) | ((uint)cvt_bf16(b) << 16);
}

// ---------------- K1: hist -> global bucket totals + w2m; last block scans ----------------
// Blocks [0,CHN): LDS hist + 196 global atomicAdds into Tg + ticket.
// Block CHN: w2m. Last-ticket hist block: coherent-read Tg, LDS scan ->
// B[] (sort bases), cur196[] (scatter cursors), row[N]=E.
__global__ void hist_w2m_kernel(const int* __restrict__ dst,
                                const float* __restrict__ W2, const float* __restrict__ b2,
                                float* __restrict__ w2m,
                                uint* __restrict__ Tg, uint* __restrict__ counter,
                                uint* __restrict__ B, uint* __restrict__ cur196,
                                int* __restrict__ row, int E, int CHN, int N) {
    int t = threadIdx.x, c = blockIdx.x;
    if (c < CHN) {                         // ---- histogram chunk ----
        __shared__ uint h[BK];
        __shared__ uint s[256];
        __shared__ uint ticket_sh;
        if (t < BK) h[t] = 0;
        __syncthreads();
        int e0 = c * CHUNK;
        for (int i = t; i < CHUNK; i += 256) {
            int e = e0 + i;
            if (e < E) atomicAdd(&h[dst[e] >> 8], 1u);
        }
        __syncthreads();
        if (t < BK && h[t]) atomicAdd(&Tg[t], h[t]);   // device-scope accumulate
        __syncthreads();                   // drain vmem (atomics performed)
        if (t == 0) {
            __threadfence();
            ticket_sh = atomicAdd(counter, 1);
        }
        __syncthreads();
        if (ticket_sh == (uint)(CHN - 1)) {            // last block: scan 196 totals
            __threadfence();
            uint v = (t < BK) ? atomicAdd(&Tg[t], 0u) : 0u;   // coherent read
            s[t] = v;
            __syncthreads();
#pragma unroll
            for (int off = 1; off < 256; off <<= 1) {
                uint u = (t >= off) ? s[t - off] : 0u;
                __syncthreads();
                s[t] += u;
                __syncthreads();
            }
            if (t < BK) {
                uint excl = s[t] - v;
                B[t] = excl;               // pristine for sort
                cur196[t] = excl;          // consumed (RMW'd) by scatter
            }
            if (t == 0) { B[BK] = (uint)E; row[N] = E; }
        }
    } else {                               // ---- w2m block ----
        if (t < 128) {
            float sum = 0.f;
            for (int j = 0; j < 128; j++) sum += W2[t * 128 + j];
            w2m[t] = sum * (1.0f / 128.0f);
        } else if (t == 128) {
            float sum = 0.f;
            for (int j = 0; j < 128; j++) sum += b2[j];
            w2m[128] = sum * (1.0f / 128.0f);
        }
    }
}

// ---------------- K2: scatter with dynamic range reservation ----------------
// Per block: LDS per-bucket count -> ONE global atomicAdd(&cur196[b], cnt)
// reserves a range -> LDS cursors place edges. Bucket-internal order is
// arbitrary (sort re-groups).
__global__ void scatter_kernel(const int* __restrict__ src, const int* __restrict__ dst,
                               uint* __restrict__ cur196, uint* __restrict__ EB,
                               int E, int CHN) {
    __shared__ uint cnt[BK];
    int t = threadIdx.x, c = blockIdx.x;
    if (t < BK) cnt[t] = 0;
    __syncthreads();
    int e0 = c * CHUNK;
    for (int i = t; i < CHUNK; i += 256) {
        int e = e0 + i;
        if (e < E) atomicAdd(&cnt[dst[e] >> 8], 1u);
    }
    __syncthreads();
    if (t < BK) {
        uint n = cnt[t];
        cnt[t] = n ? atomicAdd(&cur196[t], n) : 0u;    // reserve [base, base+n)
    }
    __syncthreads();
    for (int i = t; i < CHUNK; i += 256) {
        int e = e0 + i;
        if (e < E) {
            int d = dst[e];
            uint slot = atomicAdd(&cnt[d >> 8], 1u);
            EB[slot] = ((uint)(d & 255) << 16) | (uint)src[e];
        }
    }
}

// ---------------- K3: bucket_sort (blocks 0..BK-1)  ||  MFMA gemm (blocks BK..) ----------------
// Sort: per-bucket counting sort by dst&255 -> esrc, row, dinv (dense writes).
// Gemm: g16[M,128] = bf16( x @ W1 )  -- UNSCALED (dinv applied per-edge in gather).
// Gemm does 128 rows/block (2 row-groups) to amortize the W1 LDS staging (R14).
#define WT_STRIDE 136
union SortGemmSmem {
    struct { uint cnt[256], s[256], cur[256]; } sort;
    u16 wt[128 * WT_STRIDE];               // 34.8 KB
};
__global__ __launch_bounds__(256) void sortgemm_kernel(
    const uint* __restrict__ EB, const uint* __restrict__ B,
    int* __restrict__ row, float* __restrict__ dinv, u16* __restrict__ esrc,
    const float* __restrict__ A, const float* __restrict__ W,
    uint* __restrict__ G32, int N, int M) {
    __shared__ SortGemmSmem sm;
    int t = threadIdx.x;

    if (blockIdx.x < BK) {                 // ---- bucket sort ----
        int b = blockIdx.x;
        uint base = B[b], ne = B[b + 1] - base;
        sm.sort.cnt[t] = 0;
        __syncthreads();
        for (uint i = t; i < ne; i += 256) atomicAdd(&sm.sort.cnt[EB[base + i] >> 16], 1u);
        __syncthreads();
        uint c = sm.sort.cnt[t];
        sm.sort.s[t] = c;
        __syncthreads();
#pragma unroll
        for (int off = 1; off < 256; off <<= 1) {
            uint u = (t >= off) ? sm.sort.s[t - off] : 0u;
            __syncthreads();
            sm.sort.s[t] += u;
            __syncthreads();
        }
        uint p = sm.sort.s[t] - c;          // exclusive prefix within bucket
        int v = (b << 8) + t;
        if (v < N) {
            row[v] = (int)(base + p);
            dinv[v] = rsqrtf((float)(c + 1u));   // +1 self-loop
        }
        sm.sort.cur[t] = base + p;
        __syncthreads();
        for (uint i = t; i < ne; i += 256) {
            uint u = EB[base + i];
            uint slot = atomicAdd(&sm.sort.cur[u >> 16], 1u);
            esrc[slot] = (u16)(u & 0xffffu);
        }
    } else {                               // ---- MFMA gemm, 128 rows/block ----
        int bid = blockIdx.x - BK;
        for (int i = t; i < 128 * 128; i += 256) {   // stage W1^T as bf16 (once)
            int k = i >> 7, n = i & 127;
            sm.wt[n * WT_STRIDE + k] = cvt_bf16(W[i]);
        }
        __syncthreads();

        int wave = t >> 6, lane = t & 63;
        int m = lane & 15, quad = lane >> 4;

#pragma unroll
        for (int rg = 0; rg < 2; rg++) {
            int rowa = bid * 128 + rg * 64 + wave * 16 + m;
            int rowc = rowa < M ? rowa : M - 1;
            const float* Arow = A + (long)rowc * D;

            short8 afrag[4];
#pragma unroll
            for (int kt = 0; kt < 4; kt++) {
                int k0 = kt * 32 + quad * 8;
                float4 f0 = *(const float4*)(Arow + k0);
                float4 f1 = *(const float4*)(Arow + k0 + 4);
                short8 af;
                af[0] = (short)cvt_bf16(f0.x); af[1] = (short)cvt_bf16(f0.y);
                af[2] = (short)cvt_bf16(f0.z); af[3] = (short)cvt_bf16(f0.w);
                af[4] = (short)cvt_bf16(f1.x); af[5] = (short)cvt_bf16(f1.y);
                af[6] = (short)cvt_bf16(f1.z); af[7] = (short)cvt_bf16(f1.w);
                afrag[kt] = af;
            }

            int orow0 = bid * 128 + rg * 64 + wave * 16;
            for (int n0 = 0; n0 < 128; n0 += 16) {
                floatx4 acc = {0.f, 0.f, 0.f, 0.f};
#pragma unroll
                for (int kt = 0; kt < 4; kt++) {
                    short8 bf = *(const short8*)(sm.wt + (n0 + m) * WT_STRIDE + kt * 32 + quad * 8);
                    acc = __builtin_amdgcn_mfma_f32_16x16x32_bf16(afrag[kt], bf, acc, 0, 0, 0);
                }
#pragma unroll
                for (int r = 0; r < 4; r++) {
                    float val = acc[r];
                    float oth = __shfl_xor(val, 1, 64);      // partner column
                    int orow = orow0 + quad * 4 + r;
                    if (orow < M && (m & 1) == 0)
                        G32[(long)orow * 64 + ((n0 + m) >> 1)] = pack_bf2(val, oth);
                }
            }
        }
    }
}

// ---------------- K4: fused gather(bf16, dinv-fma) + leakyrelu + dot(w2m) ----------------
// R9b VERBATIM: one wave/node; 8 chains x 8 lanes; 2 uint4/edge, 2-deep pipeline.
// dinv[src] applied per edge via fma (g is unscaled).
__global__ __launch_bounds__(256) void gather_node_kernel(
    const int* __restrict__ row, const u16* __restrict__ esrc,
    const uint* __restrict__ g16, const float* __restrict__ dinv,
    const float* __restrict__ b1, const float* __restrict__ w2m,
    float* __restrict__ mg, int N) {
    int wave = threadIdx.x >> 6;
    int lane = threadIdx.x & 63;
    int sub = lane & 7;        // 16-channel slice: uint4 pair 2*sub, 2*sub+1
    int nb = lane >> 3;        // 8 neighbor chains
    int v = blockIdx.x * 4 + wave;
    if (v >= N) return;

    const uint4* gv = (const uint4*)g16;   // 16 uint4 per 256B row
    float dvv = dinv[v];
    float acc[16];
#pragma unroll
    for (int i = 0; i < 16; i++) acc[i] = 0.f;

#define ACC8(ua, ub, wgt) {                                              \
    uint uu[8] = {(ua).x, (ua).y, (ua).z, (ua).w, (ub).x, (ub).y, (ub).z, (ub).w}; \
    _Pragma("unroll")                                                    \
    for (int i = 0; i < 8; i++) {                                        \
        acc[2*i]   += (wgt) * __uint_as_float(uu[i] << 16);              \
        acc[2*i+1] += (wgt) * __uint_as_float(uu[i] & 0xffff0000u);      \
    } }

    if (nb == 0) {             // self-loop term: dinv[v]*h[v]
        long rb = (long)v * 16 + 2 * sub;
        uint4 ua = gv[rb], ub = gv[rb + 1];
        ACC8(ua, ub, dvv)
    }
    int jb = row[v], je = row[v + 1];
    int j = jb + nb;
    if (j < je) {              // 2-deep pipeline per chain
        int s0 = esrc[j];
        float wA = dinv[s0];
        long r0 = (long)s0 * 16 + 2 * sub;
        uint4 p0 = gv[r0], p1 = gv[r0 + 1];
        j += 8;
        while (j < je) {
            int s1 = esrc[j];
            float wB = dinv[s1];
            long r1 = (long)s1 * 16 + 2 * sub;
            uint4 q0 = gv[r1], q1 = gv[r1 + 1];
            j += 8;
            ACC8(p0, p1, wA)
            p0 = q0; p1 = q1; wA = wB;
        }
        ACC8(p0, p1, wA)
    }
#undef ACC8

    // reduce the 8 chains
#pragma unroll
    for (int i = 0; i < 16; i++) {
        acc[i] += __shfl_xor(acc[i], 8, 64);
        acc[i] += __shfl_xor(acc[i], 16, 64);
        acc[i] += __shfl_xor(acc[i], 32, 64);
    }

    if (nb == 0) {             // lane sub holds channels 16*sub .. 16*sub+15
        const float4* bp = (const float4*)b1;
        const float4* wp = (const float4*)w2m;
        float s = 0.f;
#pragma unroll
        for (int q4 = 0; q4 < 4; q4++) {
            float4 bb = bp[sub * 4 + q4];
            float4 wm = wp[sub * 4 + q4];
            float t0 = dvv * acc[4*q4 + 0] + bb.x; t0 = t0 >= 0.f ? t0 : 0.1f * t0;
            float t1 = dvv * acc[4*q4 + 1] + bb.y; t1 = t1 >= 0.f ? t1 : 0.1f * t1;
            float t2 = dvv * acc[4*q4 + 2] + bb.z; t2 = t2 >= 0.f ? t2 : 0.1f * t2;
            float t3 = dvv * acc[4*q4 + 3] + bb.w; t3 = t3 >= 0.f ? t3 : 0.1f * t3;
            s += t0 * wm.x + t1 * wm.y + t2 * wm.z + t3 * wm.w;
        }
        s += __shfl_xor(s, 1, 64);
        s += __shfl_xor(s, 2, 64);
        s += __shfl_xor(s, 4, 64);
        if (sub == 0) mg[v] = dvv * s;
    }
}

// ---------------- K5: scalar aggregate for conv2 + mean ----------------
__global__ void out_kernel(const int* __restrict__ row, const u16* __restrict__ esrc,
                           const float* __restrict__ mg, const float* __restrict__ dinv,
                           const float* __restrict__ w2m, float* __restrict__ out, int N) {
    int v = blockIdx.x * blockDim.x + threadIdx.x;
    if (v >= N) return;
    float acc = mg[v];
    int jb = row[v], je = row[v + 1];
    int j = jb;
    for (; j + 8 <= je; j += 8) {
        acc += mg[esrc[j]] + mg[esrc[j + 1]] + mg[esrc[j + 2]] + mg[esrc[j + 3]] +
               mg[esrc[j + 4]] + mg[esrc[j + 5]] + mg[esrc[j + 6]] + mg[esrc[j + 7]];
    }
    for (; j < je; j++) acc += mg[esrc[j]];
    out[v] = dinv[v] * acc + w2m[128];
}

extern "C" void kernel_launch(void* const* d_in, const int* in_sizes, int n_in,
                              void* d_out, int out_size, void* d_ws, size_t ws_size,
                              hipStream_t stream) {
    const float* x  = (const float*)d_in[0];
    const int* ei   = (const int*)d_in[1];
    const float* W1 = (const float*)d_in[2];
    const float* b1 = (const float*)d_in[3];
    const float* W2 = (const float*)d_in[4];
    const float* b2 = (const float*)d_in[5];
    float* out = (float*)d_out;

    const int N = N_NODES;
    const int E = in_sizes[1] / 2;
    const int* src = ei;
    const int* dst = ei + E;
    const int CHN = (E + CHUNK - 1) / CHUNK;   // 391
    const int nblocks = (N + 255) / 256;       // 196
    const int GB = (N + 127) / 128;            // 391 gemm blocks (128 rows each)

    // workspace (4B units). H deleted (R18). EB NOT aliased with g16.
    float*    dinv    = (float*)d_ws;                     // [NPAD]
    int*      row     = (int*)(dinv + NPAD);              // [NPAD+16]
    uint*     B       = (uint*)(row + NPAD + 16);         // [256] (BK+1 used)
    float*    w2m     = (float*)(B + 256);                // [256] ([128]=mean b2)
    float*    mg      = w2m + 256;                        // [NPAD]
    uint*     Tg      = (uint*)(mg + NPAD);               // [256] bucket totals  } memset
    uint*     counter = Tg + 256;                         // [16]  ticket         } region
    uint*     cur196  = counter + 16;                     // [256] scatter cursors
    uint*     g16u    = cur196 + 256;                     // [NPAD*64] (16B aligned)
    u16*      esrc    = (u16*)(g16u + (long)NPAD * 64);   // [E] u16
    uint*     EB      = (uint*)(esrc + E);                // [E]

    // M0: zero Tg[256] + counter[16] (graph DMA node; capture-proven R13)
    hipMemsetAsync(Tg, 0, 272 * sizeof(uint), stream);

    // K1: hist -> Tg + w2m; last-ticket block scans -> B, cur196, row[N]
    hist_w2m_kernel<<<CHN + 1, 256, 0, stream>>>(dst, W2, b2, w2m, Tg, counter,
                                                 B, cur196, row, E, CHN, N);
    // K2: scatter with dynamic range reservation
    scatter_kernel<<<CHN, 256, 0, stream>>>(src, dst, cur196, EB, E, CHN);
    // K3: bucket sort (196 blocks) || MFMA gemm (391 blocks, 128 rows each)
    sortgemm_kernel<<<BK + GB, 256, 0, stream>>>(EB, B, row, dinv, esrc,
                                                 x, W1, g16u, N, N);
    // K4: gather + lrelu + dot -> mg (R9b verbatim)
    gather_node_kernel<<<(N + 3) / 4, 256, 0, stream>>>(row, esrc, g16u, dinv, b1, w2m, mg, N);
    // K5: scalar aggregate + mean -> out
    out_kernel<<<nblocks, 256, 0, stream>>>(row, esrc, mg, dinv, w2m, out, N);
}